// Round 18
// baseline (1743.069 us; speedup 1.0000x reference)
//
#include <hip/hip_runtime.h>
#include <math.h>

typedef unsigned short u16;
typedef unsigned int   u32;
typedef __attribute__((ext_vector_type(8))) short short8;   // 8 x bf16 (4 VGPRs)
typedef __attribute__((ext_vector_type(4))) float f32x4;

#define B_  4
#define T_  4096
#define D_  1024
#define H_  16
#define DH_ 64
#define F_  4096
#define EPS_ 1e-5f
#define QKV_LD (3 * D_)

// softmax uses exp2(q.k * log2e/8); fold the whole scale into Q at QKV-GEMM time
#define QSCALE_ 0.18033688011112042f   // log2(e)/8

// ---------------- bf16 helpers (storage-only; all math fp32) ----------------
__device__ __forceinline__ float b2f(u16 v) {
    union { u32 u; float f; } x; x.u = ((u32)v) << 16; return x.f;
}
__device__ __forceinline__ u16 f2b(float f) {
    union { u32 u; float f; } x; x.f = f;
    u32 r = (x.u >> 16) & 1u;
    return (u16)((x.u + 0x7fffu + r) >> 16);
}

// raw v_exp_f32: r = 2^x, one transcendental instruction (exp2f w/o fast-math
// lowers to the branchy __ocml_exp2_f32 library call — measured +12pt VALUBusy).
__device__ __forceinline__ float ex2(float x) {
    float r;
    asm("v_exp_f32 %0, %1" : "=v"(r) : "v"(x));
    return r;
}
// raw v_rcp_f32 (~1 ulp) — same rationale as ex2
__device__ __forceinline__ float rcp_(float x) {
    float r;
    asm("v_rcp_f32 %0, %1" : "=v"(r) : "v"(x));
    return r;
}
// pack two f32 -> 2x bf16 (RNE), single VALU op (no builtin on gfx950)
__device__ __forceinline__ u32 cvtpk(float lo, float hi) {
    u32 r;
    asm("v_cvt_pk_bf16_f32 %0, %1, %2" : "=v"(r) : "v"(lo), "v"(hi));
    return r;
}
// DPP cross-lane move within 16-lane rows; CTRL: 0x101|N=row_shl:N, 0x111|N=row_shr:N
template<int CTRL>
__device__ __forceinline__ u32 dppu(u32 v) {
    return (u32)__builtin_amdgcn_update_dpp(0, (int)v, CTRL, 0xF, 0xF, true);
}

// exact-GELU via Abramowitz-Stegun 7.1.26 erf: |err| < 1.5e-7, far below the
// bf16 output quantum.
__device__ __forceinline__ float gelu_erf(float x) {
    const float z = fabsf(x) * 0.70710678118654752f;
    const float t = rcp_(1.0f + 0.3275911f * z);
    float poly = 1.061405429f;
    poly = poly * t - 1.453152027f;
    poly = poly * t + 1.421413741f;
    poly = poly * t - 0.284496736f;
    poly = poly * t + 0.254829592f;
    poly = poly * t;
    const float e = ex2(-z * z * 1.4426950408889634f);   // e^{-z^2}
    const float erfz = 1.0f - poly * e;                   // erf(z), z >= 0
    const float se = copysignf(erfz, x);
    return 0.5f * x * (1.0f + se);
}

// async global->LDS, 16 bytes per lane (lane's data lands at ldsbase + lane*16)
__device__ __forceinline__ void gll16(const u16* g, u16* ldsbase) {
    __builtin_amdgcn_global_load_lds(
        (const __attribute__((address_space(1))) void*)g,
        (__attribute__((address_space(3))) void*)ldsbase, 16, 0, 0);
}

// ---------------------------------------------------------------------------
// x (f32) -> bf16, elementwise, float4 per thread.
// ---------------------------------------------------------------------------
__global__ __launch_bounds__(256) void conv_bf16_kernel(
    const float* __restrict__ in, u16* __restrict__ out)
{
    const int i = blockIdx.x * 256 + threadIdx.x;
    float4 v = ((const float4*)in)[i];
    ushort4 o;
    o.x = f2b(v.x); o.y = f2b(v.y); o.z = f2b(v.z); o.w = f2b(v.w);
    ((ushort4*)out)[i] = o;
}

// ---------------------------------------------------------------------------
// W [R,C] f32 row-major -> Wt [C,R] bf16 row-major. 32x32 LDS tiles.
// ---------------------------------------------------------------------------
__global__ __launch_bounds__(256) void transpose_bf16_kernel(
    const float* __restrict__ W, u16* __restrict__ Wt, int R, int C)
{
    __shared__ float tile[32][33];
    const int bx = blockIdx.x * 32;
    const int by = blockIdx.y * 32;
    const int tx = threadIdx.x & 31, ty = threadIdx.x >> 5;
#pragma unroll
    for (int p = 0; p < 4; ++p)
        tile[ty + p * 8][tx] = W[(size_t)(by + ty + p * 8) * C + bx + tx];
    __syncthreads();
#pragma unroll
    for (int p = 0; p < 4; ++p)
        Wt[(size_t)(bx + ty + p * 8) * R + by + tx] = f2b(tile[tx][ty + p * 8]);
}

// ---------------------------------------------------------------------------
// MFMA GEMM: C[M,N] = act(A[M,K]bf16 @ Bt[N,K]bf16^T + bias)  (+= if acc)
// 128x128 tile, BK=32*KU, 256 threads = 4 waves (2x2 of 64x64).
// KU=1: 32 KiB LDS, 4 blocks/CU. KU=2: 64 KiB LDS, BK=64 — W2 only (its
// 512-block grid caps occupancy at 2/CU anyway; halves barrier count).
// XCD-aware block swizzle (T1, bijective; all grids %8==0).
// qcols: output columns < qcols are scaled by QSCALE_ (Q pre-scale for attn).
// ---------------------------------------------------------------------------
template<bool CBF, int KU>
__global__ __launch_bounds__(256) void mfma_gemm(
    const u16* __restrict__ A, int lda,
    const u16* __restrict__ Bt, int ldbt,
    const float* __restrict__ bias,
    void* __restrict__ Cv, int ldc,
    int K, int act, int acc, int qcols)
{
    __shared__ __align__(16) u16 Al[KU][128 * 32];
    __shared__ __align__(16) u16 Bl[KU][128 * 32];

    const int tid  = threadIdx.x;
    const int lane = tid & 63, wave = tid >> 6;
    const int quad = lane >> 4, l16 = lane & 15;

    const int gx = gridDim.x;
    const int nwg = gx * gridDim.y;
    const int lin = blockIdx.y * gx + blockIdx.x;
    const int wg  = (lin & 7) * (nwg >> 3) + (lin >> 3);
    const int m0 = (wg / gx) * 128, n0 = (wg % gx) * 128;

    const int wm = (wave >> 1) * 64, wn = (wave & 1) * 64;

    int srow[2], sgk[2];
#pragma unroll
    for (int t = 0; t < 2; ++t) {
        const int c = wave * 128 + t * 64 + lane;
        srow[t] = c >> 2;
        sgk[t] = ((c & 3) ^ ((srow[t] >> 1) & 3)) * 8;
    }
    const u16* Ag = A  + (size_t)m0 * lda;
    const u16* Bg = Bt + (size_t)n0 * ldbt;
    const int apos = (quad ^ ((l16 >> 1) & 3)) * 8;

    f32x4 accr[4][4];
#pragma unroll
    for (int i = 0; i < 4; ++i)
#pragma unroll
        for (int j = 0; j < 4; ++j)
            accr[i][j] = (f32x4)(0.0f);

    for (int k0 = 0; k0 < K; k0 += 32 * KU) {
        __syncthreads();
#pragma unroll
        for (int h = 0; h < KU; ++h)
#pragma unroll
            for (int t = 0; t < 2; ++t) {
                gll16(Ag + (size_t)srow[t] * lda  + k0 + h * 32 + sgk[t],
                      &Al[h][(wave * 128 + t * 64) * 8]);
                gll16(Bg + (size_t)srow[t] * ldbt + k0 + h * 32 + sgk[t],
                      &Bl[h][(wave * 128 + t * 64) * 8]);
            }
        __syncthreads();

#pragma unroll
        for (int h = 0; h < KU; ++h) {
            short8 af[4], bf[4];
#pragma unroll
            for (int i = 0; i < 4; ++i)
                af[i] = *(const short8*)&Al[h][(wm + i * 16 + l16) * 32 + apos];
#pragma unroll
            for (int j = 0; j < 4; ++j)
                bf[j] = *(const short8*)&Bl[h][(wn + j * 16 + l16) * 32 + apos];
#pragma unroll
            for (int i = 0; i < 4; ++i)
#pragma unroll
                for (int j = 0; j < 4; ++j)
                    accr[i][j] = __builtin_amdgcn_mfma_f32_16x16x32_bf16(
                        af[i], bf[j], accr[i][j], 0, 0, 0);
        }
    }

#pragma unroll
    for (int j = 0; j < 4; ++j) {
        const int cc = n0 + wn + j * 16 + l16;
        float bv = acc ? 0.0f : bias[cc];
        const float sc = (cc < qcols) ? QSCALE_ : 1.0f;
#pragma unroll
        for (int i = 0; i < 4; ++i) {
#pragma unroll
            for (int r = 0; r < 4; ++r) {
                const int rr = m0 + wm + i * 16 + quad * 4 + r;
                float v = (accr[i][j][r] + bv) * sc;
                if (act == 1)
                    v = gelu_erf(v);
                if (CBF) {
                    ((u16*)Cv)[(size_t)rr * ldc + cc] = f2b(v);
                } else {
                    float* dst = (float*)Cv + (size_t)rr * ldc + cc;
                    if (acc) v += *dst;
                    *dst = v;
                }
            }
        }
    }
}

// ---------------------------------------------------------------------------
// MFMA flash attention — round-15 structure + ROUND 18: fit VGPR <= 64.
// Round-16 decoded hipcc's __launch_bounds__ 2nd arg as CUDA-style min
// BLOCKS/CU: (512,8) -> 64 waves/CU -> 512/16 = 32 VGPR (catastrophic
// spill). Correct target: (512,4) -> 32 waves/CU = 8 waves/SIMD -> 64 VGPR.
// At VGPR=72 the occupancy step (m69: halves at 64/128/256) leaves HALF the
// TLP on the table; this kernel is TLP-bound (rounds 10/13, both directions).
// To fit 64 without spill, shave ~10 persistent regs: l-accumulation moves
// from MFMA-ones (l_acc f32x4[2] + ones8 = 12 regs, 8 mfma/iter) to f32
// partial sums (l_part float[2] = 2 regs): each lane's sa covers 16 of 64
// keys for its q-col; epilogue shfl_xor(16)+shfl_xor(32) over quad groups
// reconstructs the exact row sum (pre-bf16 f32 semantics = rounds 0-8,
// verified). Spill detector: hbm_bytes per dispatch (~84 MB if clean).
// ---------------------------------------------------------------------------
__global__ __launch_bounds__(512, 4) void attn_mfma_kernel(
    const u16* __restrict__ qkv, u16* __restrict__ ctx)
{
    __shared__ u16 Ks[128 * 72];     // 128 keys x 64 dh (pad 72)
    __shared__ u16 Vt[64 * 144];     // Vt[dh][key' 0..127], stride 144

    const int tid  = threadIdx.x;
    const int lane = tid & 63, wave = tid >> 6;   // 8 waves
    const int quad = lane >> 4, l16 = lane & 15;
    const bool hi  = lane >= 32;
    const int bpa  = (lane ^ 32) << 2;   // ds_bpermute byte addr of partner lane

    // XCD swizzle (gx*gy*gz = 16*16*4 = 1024, divisible by 8)
    const int gx = gridDim.x, gy = gridDim.y;
    const int nwg = gx * gy * gridDim.z;
    const int lin = (blockIdx.z * gy + blockIdx.y) * gx + blockIdx.x;
    const int wg  = (lin & 7) * (nwg >> 3) + (lin >> 3);
    const int q0 = (wg % gx) * 256;
    const int h  = (wg / gx) % gy;
    const int b  = wg / (gx * gy);

    short8 aq[2][2];
    {
        const u16* qb = qkv + (size_t)(b * T_ + q0 + wave * 32) * QKV_LD + h * DH_;
#pragma unroll
        for (int u = 0; u < 2; ++u)
#pragma unroll
            for (int s = 0; s < 2; ++s)
                aq[u][s] = *(const short8*)(qb + (size_t)(u * 16 + l16) * QKV_LD + s * 32 + quad * 8);
    }

    const int srow = tid >> 3;                 // 0..63 (8 threads per key row)
    const int scol = (tid & 7) * 8;
    const int odd8 = srow & 1;                 // key-pair parity (lanes tid vs tid+8)
    const u16* kg = qkv + (size_t)(b * T_) * QKV_LD + D_     + h * DH_;
    const u16* vg = qkv + (size_t)(b * T_) * QKV_LD + 2 * D_ + h * DH_;

    // prefetch tile 0 (128 keys = 2 halves) into registers
    short8 kreg[2], vreg[2];
#pragma unroll
    for (int hh = 0; hh < 2; ++hh) {
        kreg[hh] = *(const short8*)(kg + (size_t)(hh * 64 + srow) * QKV_LD + scol);
        vreg[hh] = *(const short8*)(vg + (size_t)(hh * 64 + srow) * QKV_LD + scol);
    }

    f32x4 o_acc[2][4];
#pragma unroll
    for (int u = 0; u < 2; ++u)
#pragma unroll
        for (int nt = 0; nt < 4; ++nt)
            o_acc[u][nt] = (f32x4)(0.0f);
    float l_part[2] = {0.0f, 0.0f};   // partial row sums (this lane's keys)

    for (int kt = 0; kt < T_; kt += 128) {
        __syncthreads();   // drains in-flight prefetch (vmcnt 0) + prev reads
#pragma unroll
        for (int hh = 0; hh < 2; ++hh) {
            const int row = hh * 64 + srow;
            *(short8*)&Ks[row * 72 + scol] = kreg[hh];

            // V transpose, key-pair packed b32 writes, PERMUTED column:
            // col(key) = swap23(key) ^ ((key&16)>>2); bits 5,6 pass through.
            union { short8 s; u32 w[4]; } vv;
            vv.s = vreg[hh];
            const u32 ws0 = dppu<0x118>(vv.w[0]);   // row_shr:8 -> lane+8 (row+1)
            const u32 ws1 = dppu<0x118>(vv.w[1]);
            const u32 sl2 = dppu<0x108>(vv.w[2]);   // row_shl:8 -> lane-8 (row-1)
            const u32 sl3 = dppu<0x108>(vv.w[3]);
            const int rowb = row & ~1;
            const int sw = ((rowb & ~12) | ((rowb & 4) << 1) | ((rowb & 8) >> 1))
                           ^ ((rowb & 16) >> 2);
            const int koff = sw ^ scol;
#pragma unroll
            for (int J = 0; J < 4; ++J) {
                const u32 wj   = vv.w[J >> 1];
                const u32 wj4  = vv.w[2 + (J >> 1)];
                const u32 wsj  = (J >> 1) ? ws1 : ws0;
                const u32 slj4 = (J >> 1) ? sl3 : sl2;
                const u32 selfJ  = (J & 1) ? (wj   >> 16) : (wj   & 0xFFFFu);
                const u32 selfJ4 = (J & 1) ? (wj4  >> 16) : (wj4  & 0xFFFFu);
                const u32 nbrJ   = (J & 1) ? (wsj  >> 16) : (wsj  & 0xFFFFu);
                const u32 nbrJ4  = (J & 1) ? (slj4 >> 16) : (slj4 & 0xFFFFu);
                const u32 lo16 = odd8 ? nbrJ4  : selfJ;   // key rowb
                const u32 hi16 = odd8 ? selfJ4 : nbrJ;    // key rowb+1
                const int dh = scol + J + (odd8 ? 4 : 0);
                *(u32*)&Vt[dh * 144 + koff] = lo16 | (hi16 << 16);
            }
        }
        __syncthreads();   // LDS tile visible; nothing vmem outstanding here

        // T14: issue next 128-key tile's loads — full 2-half compute covers them
        if (kt + 128 < T_) {
#pragma unroll
            for (int hh = 0; hh < 2; ++hh) {
                kreg[hh] = *(const short8*)(kg + (size_t)(kt + 128 + hh * 64 + srow) * QKV_LD + scol);
                vreg[hh] = *(const short8*)(vg + (size_t)(kt + 128 + hh * 64 + srow) * QKV_LD + scol);
            }
        }

#pragma unroll
        for (int s2 = 0; s2 < 2; ++s2) {
            // ---- S^T = K @ Q'^T ----
            f32x4 sa[2][4];
#pragma unroll
            for (int u = 0; u < 2; ++u)
#pragma unroll
                for (int nt = 0; nt < 4; ++nt)
                    sa[u][nt] = (f32x4)(0.0f);
            __builtin_amdgcn_s_setprio(1);
#pragma unroll
            for (int s = 0; s < 2; ++s) {
                short8 kb[4];
#pragma unroll
                for (int nt = 0; nt < 4; ++nt)
                    kb[nt] = *(const short8*)&Ks[(s2 * 64 + nt * 16 + l16) * 72 + s * 32 + quad * 8];
#pragma unroll
                for (int u = 0; u < 2; ++u)
#pragma unroll
                    for (int nt = 0; nt < 4; ++nt)
                        sa[u][nt] = __builtin_amdgcn_mfma_f32_16x16x32_bf16(
                            kb[nt], aq[u][s], sa[u][nt], 0, 0, 0);
            }
            __builtin_amdgcn_s_setprio(0);

            // ---- softmax in-register: p = 2^s'; f32 partial sums; pack ----
            u32 pk[2][4][2];
#pragma unroll
            for (int u = 0; u < 2; ++u) {
                float ls = 0.0f;
#pragma unroll
                for (int nt = 0; nt < 4; ++nt) {
#pragma unroll
                    for (int w = 0; w < 2; ++w) {
                        const float e0 = ex2(sa[u][nt][2 * w]);
                        const float e1 = ex2(sa[u][nt][2 * w + 1]);
                        ls += e0 + e1;
                        pk[u][nt][w] = cvtpk(e0, e1);
                    }
                }
                l_part[u] += ls;
            }

            // ---- PV: pb = P^T fragment from registers; O^T += V^T @ P^T ----
            __builtin_amdgcn_s_setprio(1);
#pragma unroll
            for (int s = 0; s < 2; ++s) {
                short8 vb[4];
#pragma unroll
                for (int nt = 0; nt < 4; ++nt) {
                    const int dh = nt * 16 + l16;
                    vb[nt] = *(const short8*)&Vt[dh * 144 + s2 * 64
                                                 + (((s * 32 + quad * 8)) ^ (dh & 56))];
                }
#pragma unroll
                for (int u = 0; u < 2; ++u) {
                    union { u32 w[4]; short8 v; } pb;
                    pb.w[0] = hi ? pk[u][2 * s + 1][0] : pk[u][2 * s][0];
                    pb.w[1] = hi ? pk[u][2 * s + 1][1] : pk[u][2 * s][1];
                    const u32 c0 = hi ? pk[u][2 * s][0] : pk[u][2 * s + 1][0];
                    const u32 c1 = hi ? pk[u][2 * s][1] : pk[u][2 * s + 1][1];
                    pb.w[2] = (u32)__builtin_amdgcn_ds_bpermute(bpa, (int)c0);
                    pb.w[3] = (u32)__builtin_amdgcn_ds_bpermute(bpa, (int)c1);
#pragma unroll
                    for (int nt = 0; nt < 4; ++nt)
                        o_acc[u][nt] = __builtin_amdgcn_mfma_f32_16x16x32_bf16(
                            vb[nt], pb.v, o_acc[u][nt], 0, 0, 0);
                }
            }
            __builtin_amdgcn_s_setprio(0);
        }
    }

    // ---- final: lane owns q = l16 (col); reduce l over quad groups ----
#pragma unroll
    for (int u = 0; u < 2; ++u) {
        float l = l_part[u];
        l += __shfl_xor(l, 16, 64);
        l += __shfl_xor(l, 32, 64);
        const float inv = rcp_(l);
        const size_t qrow = (size_t)(b * T_ + q0 + wave * 32 + u * 16 + l16);
#pragma unroll
        for (int nt = 0; nt < 4; ++nt) {
            uint2 o;
            o.x = cvtpk(o_acc[u][nt][0] * inv, o_acc[u][nt][1] * inv);
            o.y = cvtpk(o_acc[u][nt][2] * inv, o_acc[u][nt][3] * inv);
            *(uint2*)&ctx[qrow * D_ + h * DH_ + nt * 16 + quad * 4] = o;
        }
    }
}

// ---------------------------------------------------------------------------
// out = LayerNorm(a + b) * g + be, one row (D=1024) per 256-thread block.
// ABF/BBF/OBF select bf16 for a / b / out. Math fp32.
// ---------------------------------------------------------------------------
template<bool ABF, bool BBF, bool OBF>
__global__ __launch_bounds__(256) void add_ln_kernel(
    const void* __restrict__ av, const void* __restrict__ bv,
    const float* __restrict__ g, const float* __restrict__ be,
    void* __restrict__ outv)
{
    const int row = blockIdx.x;
    const int tid = threadIdx.x;

    float v[4];
    if (ABF) {
        ushort4 va = *(const ushort4*)((const u16*)av + (size_t)row * D_ + tid * 4);
        v[0] = b2f(va.x); v[1] = b2f(va.y); v[2] = b2f(va.z); v[3] = b2f(va.w);
    } else {
        float4 va = *(const float4*)((const float*)av + (size_t)row * D_ + tid * 4);
        v[0] = va.x; v[1] = va.y; v[2] = va.z; v[3] = va.w;
    }
    if (BBF) {
        ushort4 vb = *(const ushort4*)((const u16*)bv + (size_t)row * D_ + tid * 4);
        v[0] += b2f(vb.x); v[1] += b2f(vb.y); v[2] += b2f(vb.z); v[3] += b2f(vb.w);
    } else {
        float4 vb = *(const float4*)((const float*)bv + (size_t)row * D_ + tid * 4);
        v[0] += vb.x; v[1] += vb.y; v[2] += vb.z; v[3] += vb.w;
    }

    float s  = v[0] + v[1] + v[2] + v[3];
    float ss = v[0]*v[0] + v[1]*v[1] + v[2]*v[2] + v[3]*v[3];
#pragma unroll
    for (int off = 32; off > 0; off >>= 1) {
        s  += __shfl_down(s,  off, 64);
        ss += __shfl_down(ss, off, 64);
    }
    __shared__ float ws[4], wss[4], stats[2];
    const int wave = tid >> 6, lane = tid & 63;
    if (lane == 0) { ws[wave] = s; wss[wave] = ss; }
    __syncthreads();
    if (tid == 0) {
        float ts  = ws[0] + ws[1] + ws[2] + ws[3];
        float tss = wss[0] + wss[1] + wss[2] + wss[3];
        float mu  = ts * (1.0f / D_);
        float var = tss * (1.0f / D_) - mu * mu;
        stats[0] = mu;
        stats[1] = rsqrtf(var + EPS_);
    }
    __syncthreads();
    const float mu = stats[0], rs = stats[1];

    const float4 g4  = *(const float4*)(g  + tid * 4);
    const float4 be4 = *(const float4*)(be + tid * 4);
    float gg[4]  = {g4.x, g4.y, g4.z, g4.w};
    float beb[4] = {be4.x, be4.y, be4.z, be4.w};
    if (OBF) {
        ushort4 o;
        o.x = f2b((v[0] - mu) * rs * gg[0] + beb[0]);
        o.y = f2b((v[1] - mu) * rs * gg[1] + beb[1]);
        o.z = f2b((v[2] - mu) * rs * gg[2] + beb[2]);
        o.w = f2b((v[3] - mu) * rs * gg[3] + beb[3]);
        *(ushort4*)((u16*)outv + (size_t)row * D_ + tid * 4) = o;
    } else {
        float4 o;
        o.x = (v[0] - mu) * rs * gg[0] + beb[0];
        o.y = (v[1] - mu) * rs * gg[1] + beb[1];
        o.z = (v[2] - mu) * rs * gg[2] + beb[2];
        o.w = (v[3] - mu) * rs * gg[3] + beb[3];
        *(float4*)((float*)outv + (size_t)row * D_ + tid * 4) = o;
    }
}

// ---------------------------------------------------------------------------
// Orchestration.
// ws (128 MB):
//   [0,96MB):  qkv bf16 (1-2)  ->  projB bf16 [0,32) (3-4)
//                               ->  hchunk bf16 [8192,F] [0,64) (5-6)
//   [64,96MB): ffn bf16 [M,D] (6-7)
//   [96,128MB): ctx bf16 (2-3) -> x1_b bf16 (4-7)
// d_out (64 MB) as scratch until phase 7:
//   x_b @ +0 (32MB), WqkvT @ +32MB, WoT @ +38MB, W1T @ +40MB, W2T @ +48MB.
// LN1 residual reads xB (bf16): -32 MB HBM (verified round 16, absmax 0.047).
// FFN chunked over M (2 x 8192 rows): W2 single-pass K=4096 (KU=2, BK=64).
// ---------------------------------------------------------------------------
extern "C" void kernel_launch(void* const* d_in, const int* in_sizes, int n_in,
                              void* d_out, int out_size, void* d_ws, size_t ws_size,
                              hipStream_t stream)
{
    const float* x    = (const float*)d_in[0];
    const float* Wqkv = (const float*)d_in[1];
    const float* bqkv = (const float*)d_in[2];
    const float* Wo   = (const float*)d_in[3];
    const float* bo   = (const float*)d_in[4];
    const float* W1   = (const float*)d_in[5];
    const float* b1   = (const float*)d_in[6];
    const float* W2   = (const float*)d_in[7];
    const float* b2   = (const float*)d_in[8];
    const float* g1   = (const float*)d_in[9];
    const float* be1  = (const float*)d_in[10];
    const float* g2   = (const float*)d_in[11];
    const float* be2  = (const float*)d_in[12];
    float* out = (float*)d_out;

    const int M = B_ * T_;   // 16384
    char* ws = (char*)d_ws;
    char* sc = (char*)d_out;

    u16*   qkvB   = (u16*)ws;                              // 96 MB @ 0
    u16*   ctxB   = (u16*)(ws + (size_t)100663296);        // 32 MB @ 96M
    u16*   projB  = (u16*)ws;                              // 32 MB @ 0
    u16*   x1B    = (u16*)(ws + (size_t)100663296);        // 32 MB @ 96M
    u16*   hchunk = (u16*)ws;                              // 64 MB @ 0
    u16*   ffnB   = (u16*)(ws + (size_t)67108864);         // 32 MB @ 64M

    u16* xB    = (u16*)sc;                                 // 32 MB
    u16* WqkvT = (u16*)(sc + (size_t)33554432);            //  6 MB
    u16* WoT   = (u16*)(sc + (size_t)39845888);            //  2 MB
    u16* W1T   = (u16*)(sc + (size_t)41943040);            //  8 MB
    u16* W2T   = (u16*)(sc + (size_t)50331648);            //  8 MB

    dim3 blk(256);

    // 0: conversions into d_out scratch
    conv_bf16_kernel<<<dim3(M * D_ / 1024), blk, 0, stream>>>(x, xB);
    transpose_bf16_kernel<<<dim3(3 * D_ / 32, D_ / 32), blk, 0, stream>>>(Wqkv, WqkvT, D_, 3 * D_);
    transpose_bf16_kernel<<<dim3(D_ / 32, D_ / 32), blk, 0, stream>>>(Wo, WoT, D_, D_);
    transpose_bf16_kernel<<<dim3(F_ / 32, D_ / 32), blk, 0, stream>>>(W1, W1T, D_, F_);
    transpose_bf16_kernel<<<dim3(D_ / 32, F_ / 32), blk, 0, stream>>>(W2, W2T, F_, D_);

    // 1: qkv = x @ Wqkv + bqkv  (Q columns pre-scaled by log2e/8)
    mfma_gemm<true, 1><<<dim3(3 * D_ / 128, M / 128), blk, 0, stream>>>(
        xB, D_, WqkvT, D_, bqkv, qkvB, 3 * D_, D_, 0, 0, D_);

    // 2: ctx = attention(qkv)  — 512 threads, QBLK=256, KVBLK=128
    attn_mfma_kernel<<<dim3(T_ / 256, H_, B_), dim3(512), 0, stream>>>(qkvB, ctxB);

    // 3: proj = ctx @ Wo + bo  (-> bf16)
    mfma_gemm<true, 1><<<dim3(D_ / 128, M / 128), blk, 0, stream>>>(
        ctxB, D_, WoT, D_, bo, projB, D_, D_, 0, 0, 0);

    // 4: x1_b = LN(xB + projB)  (bf16 residual read: -32 MB HBM)
    add_ln_kernel<true, true, true><<<dim3(M), blk, 0, stream>>>(xB, projB, g1, be1, x1B);

    // 5+6: FFN chunked over M (2 x 8192 rows); W2 uses KU=2 (BK=64):
    // its 512-block grid caps occupancy at 2 blocks/CU anyway, so the
    // 64 KiB LDS costs nothing and halves the K-loop barrier count.
    for (int mc = 0; mc < 2; ++mc) {
        const size_t m0 = (size_t)mc * 8192;
        mfma_gemm<true, 1><<<dim3(F_ / 128, 8192 / 128), blk, 0, stream>>>(
            x1B + m0 * D_, D_, W1T, D_, b1, hchunk, F_, D_, 1, 0, 0);
        mfma_gemm<true, 2><<<dim3(D_ / 128, 8192 / 128), blk, 0, stream>>>(
            hchunk, F_, W2T, F_, b2, ffnB + m0 * D_, D_, F_, 0, 0, 0);
    }

    // 7: out = LN(x1 + ffn) -> d_out (f32), overwrites scratch
    add_ln_kernel<true, true, false><<<dim3(M), blk, 0, stream>>>(x1B, ffnB, g2, be2, out);
}

// Round 20
// 997.279 us; speedup vs baseline: 1.7478x; 1.7478x over previous
//
#include <hip/hip_runtime.h>
#include <math.h>

typedef unsigned short u16;
typedef unsigned int   u32;
typedef __attribute__((ext_vector_type(8))) short short8;   // 8 x bf16 (4 VGPRs)
typedef __attribute__((ext_vector_type(4))) float f32x4;

#define B_  4
#define T_  4096
#define D_  1024
#define H_  16
#define DH_ 64
#define F_  4096
#define EPS_ 1e-5f
#define QKV_LD (3 * D_)

// softmax uses exp2(q.k * log2e/8); fold the whole scale into Q at QKV-GEMM time
#define QSCALE_ 0.18033688011112042f   // log2(e)/8

// ---------------- bf16 helpers (storage-only; all math fp32) ----------------
__device__ __forceinline__ float b2f(u16 v) {
    union { u32 u; float f; } x; x.u = ((u32)v) << 16; return x.f;
}
__device__ __forceinline__ u16 f2b(float f) {
    union { u32 u; float f; } x; x.f = f;
    u32 r = (x.u >> 16) & 1u;
    return (u16)((x.u + 0x7fffu + r) >> 16);
}

// raw v_exp_f32: r = 2^x, one transcendental instruction (exp2f w/o fast-math
// lowers to the branchy __ocml_exp2_f32 library call — measured +12pt VALUBusy).
__device__ __forceinline__ float ex2(float x) {
    float r;
    asm("v_exp_f32 %0, %1" : "=v"(r) : "v"(x));
    return r;
}
// raw v_rcp_f32 (~1 ulp) — same rationale as ex2
__device__ __forceinline__ float rcp_(float x) {
    float r;
    asm("v_rcp_f32 %0, %1" : "=v"(r) : "v"(x));
    return r;
}
// pack two f32 -> 2x bf16 (RNE), single VALU op (no builtin on gfx950)
__device__ __forceinline__ u32 cvtpk(float lo, float hi) {
    u32 r;
    asm("v_cvt_pk_bf16_f32 %0, %1, %2" : "=v"(r) : "v"(lo), "v"(hi));
    return r;
}
// DPP cross-lane move within 16-lane rows; CTRL: 0x101|N=row_shl:N, 0x111|N=row_shr:N
template<int CTRL>
__device__ __forceinline__ u32 dppu(u32 v) {
    return (u32)__builtin_amdgcn_update_dpp(0, (int)v, CTRL, 0xF, 0xF, true);
}

// exact-GELU via Abramowitz-Stegun 7.1.26 erf: |err| < 1.5e-7, far below the
// bf16 output quantum.
__device__ __forceinline__ float gelu_erf(float x) {
    const float z = fabsf(x) * 0.70710678118654752f;
    const float t = rcp_(1.0f + 0.3275911f * z);
    float poly = 1.061405429f;
    poly = poly * t - 1.453152027f;
    poly = poly * t + 1.421413741f;
    poly = poly * t - 0.284496736f;
    poly = poly * t + 0.254829592f;
    poly = poly * t;
    const float e = ex2(-z * z * 1.4426950408889634f);   // e^{-z^2}
    const float erfz = 1.0f - poly * e;                   // erf(z), z >= 0
    const float se = copysignf(erfz, x);
    return 0.5f * x * (1.0f + se);
}

// async global->LDS, 16 bytes per lane (lane's data lands at ldsbase + lane*16)
__device__ __forceinline__ void gll16(const u16* g, u16* ldsbase) {
    __builtin_amdgcn_global_load_lds(
        (const __attribute__((address_space(1))) void*)g,
        (__attribute__((address_space(3))) void*)ldsbase, 16, 0, 0);
}

// ---------------------------------------------------------------------------
// x (f32) -> bf16, elementwise, float4 per thread.
// ---------------------------------------------------------------------------
__global__ __launch_bounds__(256) void conv_bf16_kernel(
    const float* __restrict__ in, u16* __restrict__ out)
{
    const int i = blockIdx.x * 256 + threadIdx.x;
    float4 v = ((const float4*)in)[i];
    ushort4 o;
    o.x = f2b(v.x); o.y = f2b(v.y); o.z = f2b(v.z); o.w = f2b(v.w);
    ((ushort4*)out)[i] = o;
}

// ---------------------------------------------------------------------------
// W [R,C] f32 row-major -> Wt [C,R] bf16 row-major. 32x32 LDS tiles.
// ---------------------------------------------------------------------------
__global__ __launch_bounds__(256) void transpose_bf16_kernel(
    const float* __restrict__ W, u16* __restrict__ Wt, int R, int C)
{
    __shared__ float tile[32][33];
    const int bx = blockIdx.x * 32;
    const int by = blockIdx.y * 32;
    const int tx = threadIdx.x & 31, ty = threadIdx.x >> 5;
#pragma unroll
    for (int p = 0; p < 4; ++p)
        tile[ty + p * 8][tx] = W[(size_t)(by + ty + p * 8) * C + bx + tx];
    __syncthreads();
#pragma unroll
    for (int p = 0; p < 4; ++p)
        Wt[(size_t)(bx + ty + p * 8) * R + by + tx] = f2b(tile[tx][ty + p * 8]);
}

// ---------------------------------------------------------------------------
// MFMA GEMM: C[M,N] = act(A[M,K]bf16 @ Bt[N,K]bf16^T + bias)  (+= if acc)
// 128x128 tile, BK=32*KU, 256 threads = 4 waves (2x2 of 64x64).
// KU=1: 32 KiB LDS, 4 blocks/CU. KU=2: 64 KiB LDS, BK=64 — W2 only (its
// 512-block grid caps occupancy at 2/CU anyway; halves barrier count).
// XCD-aware block swizzle (T1, bijective; all grids %8==0).
// qcols: output columns < qcols are scaled by QSCALE_ (Q pre-scale for attn).
// ---------------------------------------------------------------------------
template<bool CBF, int KU>
__global__ __launch_bounds__(256) void mfma_gemm(
    const u16* __restrict__ A, int lda,
    const u16* __restrict__ Bt, int ldbt,
    const float* __restrict__ bias,
    void* __restrict__ Cv, int ldc,
    int K, int act, int acc, int qcols)
{
    __shared__ __align__(16) u16 Al[KU][128 * 32];
    __shared__ __align__(16) u16 Bl[KU][128 * 32];

    const int tid  = threadIdx.x;
    const int lane = tid & 63, wave = tid >> 6;
    const int quad = lane >> 4, l16 = lane & 15;

    const int gx = gridDim.x;
    const int nwg = gx * gridDim.y;
    const int lin = blockIdx.y * gx + blockIdx.x;
    const int wg  = (lin & 7) * (nwg >> 3) + (lin >> 3);
    const int m0 = (wg / gx) * 128, n0 = (wg % gx) * 128;

    const int wm = (wave >> 1) * 64, wn = (wave & 1) * 64;

    int srow[2], sgk[2];
#pragma unroll
    for (int t = 0; t < 2; ++t) {
        const int c = wave * 128 + t * 64 + lane;
        srow[t] = c >> 2;
        sgk[t] = ((c & 3) ^ ((srow[t] >> 1) & 3)) * 8;
    }
    const u16* Ag = A  + (size_t)m0 * lda;
    const u16* Bg = Bt + (size_t)n0 * ldbt;
    const int apos = (quad ^ ((l16 >> 1) & 3)) * 8;

    f32x4 accr[4][4];
#pragma unroll
    for (int i = 0; i < 4; ++i)
#pragma unroll
        for (int j = 0; j < 4; ++j)
            accr[i][j] = (f32x4)(0.0f);

    for (int k0 = 0; k0 < K; k0 += 32 * KU) {
        __syncthreads();
#pragma unroll
        for (int h = 0; h < KU; ++h)
#pragma unroll
            for (int t = 0; t < 2; ++t) {
                gll16(Ag + (size_t)srow[t] * lda  + k0 + h * 32 + sgk[t],
                      &Al[h][(wave * 128 + t * 64) * 8]);
                gll16(Bg + (size_t)srow[t] * ldbt + k0 + h * 32 + sgk[t],
                      &Bl[h][(wave * 128 + t * 64) * 8]);
            }
        __syncthreads();

#pragma unroll
        for (int h = 0; h < KU; ++h) {
            short8 af[4], bf[4];
#pragma unroll
            for (int i = 0; i < 4; ++i)
                af[i] = *(const short8*)&Al[h][(wm + i * 16 + l16) * 32 + apos];
#pragma unroll
            for (int j = 0; j < 4; ++j)
                bf[j] = *(const short8*)&Bl[h][(wn + j * 16 + l16) * 32 + apos];
#pragma unroll
            for (int i = 0; i < 4; ++i)
#pragma unroll
                for (int j = 0; j < 4; ++j)
                    accr[i][j] = __builtin_amdgcn_mfma_f32_16x16x32_bf16(
                        af[i], bf[j], accr[i][j], 0, 0, 0);
        }
    }

#pragma unroll
    for (int j = 0; j < 4; ++j) {
        const int cc = n0 + wn + j * 16 + l16;
        float bv = acc ? 0.0f : bias[cc];
        const float sc = (cc < qcols) ? QSCALE_ : 1.0f;
#pragma unroll
        for (int i = 0; i < 4; ++i) {
#pragma unroll
            for (int r = 0; r < 4; ++r) {
                const int rr = m0 + wm + i * 16 + quad * 4 + r;
                float v = (accr[i][j][r] + bv) * sc;
                if (act == 1)
                    v = gelu_erf(v);
                if (CBF) {
                    ((u16*)Cv)[(size_t)rr * ldc + cc] = f2b(v);
                } else {
                    float* dst = (float*)Cv + (size_t)rr * ldc + cc;
                    if (acc) v += *dst;
                    *dst = v;
                }
            }
        }
    }
}

// ---------------------------------------------------------------------------
// MFMA flash attention — ROUND-17 CONFIG (verified 339.6 us, total 999.4).
// VGPR=72 @ 7 waves/SIMD is this structure's floor: forcing 64 via
// __launch_bounds__ 2nd arg spilled both at (512,8)->32 VGPR (r16, 2465us)
// and (512,4)->64 VGPR (r18, 1072us, 5GB scratch traffic). Live set needs
// >64; the occupancy step at 64 is unreachable without a structural shrink
// that costs more TLP than it gains (r13). Do NOT cap registers.
// Structure: 512 threads, QBLK=256, KVBLK=128; swapped QK^T, in-register P;
// T14 prefetch (full 2-half compute window); MFMA-ones row sums; T5 setprio;
// XCD swizzle; Q pre-scale + raw v_exp_f32.
// ---------------------------------------------------------------------------
__global__ __launch_bounds__(512) void attn_mfma_kernel(
    const u16* __restrict__ qkv, u16* __restrict__ ctx)
{
    __shared__ u16 Ks[128 * 72];     // 128 keys x 64 dh (pad 72)
    __shared__ u16 Vt[64 * 144];     // Vt[dh][key' 0..127], stride 144

    const int tid  = threadIdx.x;
    const int lane = tid & 63, wave = tid >> 6;   // 8 waves
    const int quad = lane >> 4, l16 = lane & 15;
    const bool hi  = lane >= 32;
    const int bpa  = (lane ^ 32) << 2;   // ds_bpermute byte addr of partner lane

    // XCD swizzle (gx*gy*gz = 16*16*4 = 1024, divisible by 8)
    const int gx = gridDim.x, gy = gridDim.y;
    const int nwg = gx * gy * gridDim.z;
    const int lin = (blockIdx.z * gy + blockIdx.y) * gx + blockIdx.x;
    const int wg  = (lin & 7) * (nwg >> 3) + (lin >> 3);
    const int q0 = (wg % gx) * 256;
    const int h  = (wg / gx) % gy;
    const int b  = wg / (gx * gy);

    short8 ones8;
#pragma unroll
    for (int i = 0; i < 8; ++i) ones8[i] = (short)0x3F80;   // bf16 1.0

    short8 aq[2][2];
    {
        const u16* qb = qkv + (size_t)(b * T_ + q0 + wave * 32) * QKV_LD + h * DH_;
#pragma unroll
        for (int u = 0; u < 2; ++u)
#pragma unroll
            for (int s = 0; s < 2; ++s)
                aq[u][s] = *(const short8*)(qb + (size_t)(u * 16 + l16) * QKV_LD + s * 32 + quad * 8);
    }

    const int srow = tid >> 3;                 // 0..63 (8 threads per key row)
    const int scol = (tid & 7) * 8;
    const int odd8 = srow & 1;                 // key-pair parity (lanes tid vs tid+8)
    const u16* kg = qkv + (size_t)(b * T_) * QKV_LD + D_     + h * DH_;
    const u16* vg = qkv + (size_t)(b * T_) * QKV_LD + 2 * D_ + h * DH_;

    // prefetch tile 0 (128 keys = 2 halves) into registers
    short8 kreg[2], vreg[2];
#pragma unroll
    for (int hh = 0; hh < 2; ++hh) {
        kreg[hh] = *(const short8*)(kg + (size_t)(hh * 64 + srow) * QKV_LD + scol);
        vreg[hh] = *(const short8*)(vg + (size_t)(hh * 64 + srow) * QKV_LD + scol);
    }

    f32x4 o_acc[2][4];
#pragma unroll
    for (int u = 0; u < 2; ++u)
#pragma unroll
        for (int nt = 0; nt < 4; ++nt)
            o_acc[u][nt] = (f32x4)(0.0f);
    f32x4 l_acc[2];
    l_acc[0] = (f32x4)(0.0f);
    l_acc[1] = (f32x4)(0.0f);

    for (int kt = 0; kt < T_; kt += 128) {
        __syncthreads();   // drains in-flight prefetch (vmcnt 0) + prev reads
#pragma unroll
        for (int hh = 0; hh < 2; ++hh) {
            const int row = hh * 64 + srow;
            *(short8*)&Ks[row * 72 + scol] = kreg[hh];

            // V transpose, key-pair packed b32 writes, PERMUTED column:
            // col(key) = swap23(key) ^ ((key&16)>>2); bits 5,6 pass through.
            union { short8 s; u32 w[4]; } vv;
            vv.s = vreg[hh];
            const u32 ws0 = dppu<0x118>(vv.w[0]);   // row_shr:8 -> lane+8 (row+1)
            const u32 ws1 = dppu<0x118>(vv.w[1]);
            const u32 sl2 = dppu<0x108>(vv.w[2]);   // row_shl:8 -> lane-8 (row-1)
            const u32 sl3 = dppu<0x108>(vv.w[3]);
            const int rowb = row & ~1;
            const int sw = ((rowb & ~12) | ((rowb & 4) << 1) | ((rowb & 8) >> 1))
                           ^ ((rowb & 16) >> 2);
            const int koff = sw ^ scol;
#pragma unroll
            for (int J = 0; J < 4; ++J) {
                const u32 wj   = vv.w[J >> 1];
                const u32 wj4  = vv.w[2 + (J >> 1)];
                const u32 wsj  = (J >> 1) ? ws1 : ws0;
                const u32 slj4 = (J >> 1) ? sl3 : sl2;
                const u32 selfJ  = (J & 1) ? (wj   >> 16) : (wj   & 0xFFFFu);
                const u32 selfJ4 = (J & 1) ? (wj4  >> 16) : (wj4  & 0xFFFFu);
                const u32 nbrJ   = (J & 1) ? (wsj  >> 16) : (wsj  & 0xFFFFu);
                const u32 nbrJ4  = (J & 1) ? (slj4 >> 16) : (slj4 & 0xFFFFu);
                const u32 lo16 = odd8 ? nbrJ4  : selfJ;   // key rowb
                const u32 hi16 = odd8 ? selfJ4 : nbrJ;    // key rowb+1
                const int dh = scol + J + (odd8 ? 4 : 0);
                *(u32*)&Vt[dh * 144 + koff] = lo16 | (hi16 << 16);
            }
        }
        __syncthreads();   // LDS tile visible; nothing vmem outstanding here

        // T14: issue next 128-key tile's loads — full 2-half compute covers them
        if (kt + 128 < T_) {
#pragma unroll
            for (int hh = 0; hh < 2; ++hh) {
                kreg[hh] = *(const short8*)(kg + (size_t)(kt + 128 + hh * 64 + srow) * QKV_LD + scol);
                vreg[hh] = *(const short8*)(vg + (size_t)(kt + 128 + hh * 64 + srow) * QKV_LD + scol);
            }
        }

#pragma unroll
        for (int s2 = 0; s2 < 2; ++s2) {
            // ---- S^T = K @ Q'^T ----
            f32x4 sa[2][4];
#pragma unroll
            for (int u = 0; u < 2; ++u)
#pragma unroll
                for (int nt = 0; nt < 4; ++nt)
                    sa[u][nt] = (f32x4)(0.0f);
            __builtin_amdgcn_s_setprio(1);
#pragma unroll
            for (int s = 0; s < 2; ++s) {
                short8 kb[4];
#pragma unroll
                for (int nt = 0; nt < 4; ++nt)
                    kb[nt] = *(const short8*)&Ks[(s2 * 64 + nt * 16 + l16) * 72 + s * 32 + quad * 8];
#pragma unroll
                for (int u = 0; u < 2; ++u)
#pragma unroll
                    for (int nt = 0; nt < 4; ++nt)
                        sa[u][nt] = __builtin_amdgcn_mfma_f32_16x16x32_bf16(
                            kb[nt], aq[u][s], sa[u][nt], 0, 0, 0);
            }
            __builtin_amdgcn_s_setprio(0);

            // ---- softmax in-register: p = 2^s', pack key pairs ----
            u32 pk[2][4][2];
#pragma unroll
            for (int u = 0; u < 2; ++u)
#pragma unroll
                for (int nt = 0; nt < 4; ++nt)
#pragma unroll
                    for (int w = 0; w < 2; ++w)
                        pk[u][nt][w] = cvtpk(ex2(sa[u][nt][2 * w]),
                                             ex2(sa[u][nt][2 * w + 1]));

            // ---- PV: pb = P^T fragment from registers; O^T += V^T @ P^T ----
            __builtin_amdgcn_s_setprio(1);
#pragma unroll
            for (int s = 0; s < 2; ++s) {
                short8 vb[4];
#pragma unroll
                for (int nt = 0; nt < 4; ++nt) {
                    const int dh = nt * 16 + l16;
                    vb[nt] = *(const short8*)&Vt[dh * 144 + s2 * 64
                                                 + (((s * 32 + quad * 8)) ^ (dh & 56))];
                }
#pragma unroll
                for (int u = 0; u < 2; ++u) {
                    union { u32 w[4]; short8 v; } pb;
                    pb.w[0] = hi ? pk[u][2 * s + 1][0] : pk[u][2 * s][0];
                    pb.w[1] = hi ? pk[u][2 * s + 1][1] : pk[u][2 * s][1];
                    const u32 c0 = hi ? pk[u][2 * s][0] : pk[u][2 * s + 1][0];
                    const u32 c1 = hi ? pk[u][2 * s][1] : pk[u][2 * s + 1][1];
                    pb.w[2] = (u32)__builtin_amdgcn_ds_bpermute(bpa, (int)c0);
                    pb.w[3] = (u32)__builtin_amdgcn_ds_bpermute(bpa, (int)c1);
                    l_acc[u] = __builtin_amdgcn_mfma_f32_16x16x32_bf16(
                        ones8, pb.v, l_acc[u], 0, 0, 0);
#pragma unroll
                    for (int nt = 0; nt < 4; ++nt)
                        o_acc[u][nt] = __builtin_amdgcn_mfma_f32_16x16x32_bf16(
                            vb[nt], pb.v, o_acc[u][nt], 0, 0, 0);
                }
            }
            __builtin_amdgcn_s_setprio(0);
        }
    }

    // ---- final: lane owns q = l16 (col); no shuffles needed ----
#pragma unroll
    for (int u = 0; u < 2; ++u) {
        const float inv = rcp_(l_acc[u][0]);
        const size_t qrow = (size_t)(b * T_ + q0 + wave * 32 + u * 16 + l16);
#pragma unroll
        for (int nt = 0; nt < 4; ++nt) {
            uint2 o;
            o.x = cvtpk(o_acc[u][nt][0] * inv, o_acc[u][nt][1] * inv);
            o.y = cvtpk(o_acc[u][nt][2] * inv, o_acc[u][nt][3] * inv);
            *(uint2*)&ctx[qrow * D_ + h * DH_ + nt * 16 + quad * 4] = o;
        }
    }
}

// ---------------------------------------------------------------------------
// out = LayerNorm(a + b) * g + be, one row (D=1024) per 256-thread block.
// ABF/BBF/OBF select bf16 for a / b / out. Math fp32.
// ---------------------------------------------------------------------------
template<bool ABF, bool BBF, bool OBF>
__global__ __launch_bounds__(256) void add_ln_kernel(
    const void* __restrict__ av, const void* __restrict__ bv,
    const float* __restrict__ g, const float* __restrict__ be,
    void* __restrict__ outv)
{
    const int row = blockIdx.x;
    const int tid = threadIdx.x;

    float v[4];
    if (ABF) {
        ushort4 va = *(const ushort4*)((const u16*)av + (size_t)row * D_ + tid * 4);
        v[0] = b2f(va.x); v[1] = b2f(va.y); v[2] = b2f(va.z); v[3] = b2f(va.w);
    } else {
        float4 va = *(const float4*)((const float*)av + (size_t)row * D_ + tid * 4);
        v[0] = va.x; v[1] = va.y; v[2] = va.z; v[3] = va.w;
    }
    if (BBF) {
        ushort4 vb = *(const ushort4*)((const u16*)bv + (size_t)row * D_ + tid * 4);
        v[0] += b2f(vb.x); v[1] += b2f(vb.y); v[2] += b2f(vb.z); v[3] += b2f(vb.w);
    } else {
        float4 vb = *(const float4*)((const float*)bv + (size_t)row * D_ + tid * 4);
        v[0] += vb.x; v[1] += vb.y; v[2] += vb.z; v[3] += vb.w;
    }

    float s  = v[0] + v[1] + v[2] + v[3];
    float ss = v[0]*v[0] + v[1]*v[1] + v[2]*v[2] + v[3]*v[3];
#pragma unroll
    for (int off = 32; off > 0; off >>= 1) {
        s  += __shfl_down(s,  off, 64);
        ss += __shfl_down(ss, off, 64);
    }
    __shared__ float ws[4], wss[4], stats[2];
    const int wave = tid >> 6, lane = tid & 63;
    if (lane == 0) { ws[wave] = s; wss[wave] = ss; }
    __syncthreads();
    if (tid == 0) {
        float ts  = ws[0] + ws[1] + ws[2] + ws[3];
        float tss = wss[0] + wss[1] + wss[2] + wss[3];
        float mu  = ts * (1.0f / D_);
        float var = tss * (1.0f / D_) - mu * mu;
        stats[0] = mu;
        stats[1] = rsqrtf(var + EPS_);
    }
    __syncthreads();
    const float mu = stats[0], rs = stats[1];

    const float4 g4  = *(const float4*)(g  + tid * 4);
    const float4 be4 = *(const float4*)(be + tid * 4);
    float gg[4]  = {g4.x, g4.y, g4.z, g4.w};
    float beb[4] = {be4.x, be4.y, be4.z, be4.w};
    if (OBF) {
        ushort4 o;
        o.x = f2b((v[0] - mu) * rs * gg[0] + beb[0]);
        o.y = f2b((v[1] - mu) * rs * gg[1] + beb[1]);
        o.z = f2b((v[2] - mu) * rs * gg[2] + beb[2]);
        o.w = f2b((v[3] - mu) * rs * gg[3] + beb[3]);
        *(ushort4*)((u16*)outv + (size_t)row * D_ + tid * 4) = o;
    } else {
        float4 o;
        o.x = (v[0] - mu) * rs * gg[0] + beb[0];
        o.y = (v[1] - mu) * rs * gg[1] + beb[1];
        o.z = (v[2] - mu) * rs * gg[2] + beb[2];
        o.w = (v[3] - mu) * rs * gg[3] + beb[3];
        *(float4*)((float*)outv + (size_t)row * D_ + tid * 4) = o;
    }
}

// ---------------------------------------------------------------------------
// Orchestration.
// ws (128 MB):
//   [0,96MB):  qkv bf16 (1-2)  ->  projB bf16 [0,32) (3-4)
//                               ->  hchunk bf16 [8192,F] [0,64) (5-6)
//   [64,96MB): ffn bf16 [M,D] (6-7)
//   [96,128MB): ctx bf16 (2-3) -> x1_b bf16 (4-7)
// d_out (64 MB) as scratch until phase 7:
//   x_b @ +0 (32MB), WqkvT @ +32MB, WoT @ +38MB, W1T @ +40MB, W2T @ +48MB.
// LN1 residual reads xB (bf16): -32 MB HBM (verified round 16, absmax 0.047).
// FFN chunked over M (2 x 8192 rows): W2 single-pass K=4096 (KU=2, BK=64).
// ---------------------------------------------------------------------------
extern "C" void kernel_launch(void* const* d_in, const int* in_sizes, int n_in,
                              void* d_out, int out_size, void* d_ws, size_t ws_size,
                              hipStream_t stream)
{
    const float* x    = (const float*)d_in[0];
    const float* Wqkv = (const float*)d_in[1];
    const float* bqkv = (const float*)d_in[2];
    const float* Wo   = (const float*)d_in[3];
    const float* bo   = (const float*)d_in[4];
    const float* W1   = (const float*)d_in[5];
    const float* b1   = (const float*)d_in[6];
    const float* W2   = (const float*)d_in[7];
    const float* b2   = (const float*)d_in[8];
    const float* g1   = (const float*)d_in[9];
    const float* be1  = (const float*)d_in[10];
    const float* g2   = (const float*)d_in[11];
    const float* be2  = (const float*)d_in[12];
    float* out = (float*)d_out;

    const int M = B_ * T_;   // 16384
    char* ws = (char*)d_ws;
    char* sc = (char*)d_out;

    u16*   qkvB   = (u16*)ws;                              // 96 MB @ 0
    u16*   ctxB   = (u16*)(ws + (size_t)100663296);        // 32 MB @ 96M
    u16*   projB  = (u16*)ws;                              // 32 MB @ 0
    u16*   x1B    = (u16*)(ws + (size_t)100663296);        // 32 MB @ 96M
    u16*   hchunk = (u16*)ws;                              // 64 MB @ 0
    u16*   ffnB   = (u16*)(ws + (size_t)67108864);         // 32 MB @ 64M

    u16* xB    = (u16*)sc;                                 // 32 MB
    u16* WqkvT = (u16*)(sc + (size_t)33554432);            //  6 MB
    u16* WoT   = (u16*)(sc + (size_t)39845888);            //  2 MB
    u16* W1T   = (u16*)(sc + (size_t)41943040);            //  8 MB
    u16* W2T   = (u16*)(sc + (size_t)50331648);            //  8 MB

    dim3 blk(256);

    // 0: conversions into d_out scratch
    conv_bf16_kernel<<<dim3(M * D_ / 1024), blk, 0, stream>>>(x, xB);
    transpose_bf16_kernel<<<dim3(3 * D_ / 32, D_ / 32), blk, 0, stream>>>(Wqkv, WqkvT, D_, 3 * D_);
    transpose_bf16_kernel<<<dim3(D_ / 32, D_ / 32), blk, 0, stream>>>(Wo, WoT, D_, D_);
    transpose_bf16_kernel<<<dim3(F_ / 32, D_ / 32), blk, 0, stream>>>(W1, W1T, D_, F_);
    transpose_bf16_kernel<<<dim3(D_ / 32, F_ / 32), blk, 0, stream>>>(W2, W2T, F_, D_);

    // 1: qkv = x @ Wqkv + bqkv  (Q columns pre-scaled by log2e/8)
    mfma_gemm<true, 1><<<dim3(3 * D_ / 128, M / 128), blk, 0, stream>>>(
        xB, D_, WqkvT, D_, bqkv, qkvB, 3 * D_, D_, 0, 0, D_);

    // 2: ctx = attention(qkv)  — 512 threads, QBLK=256, KVBLK=128
    attn_mfma_kernel<<<dim3(T_ / 256, H_, B_), dim3(512), 0, stream>>>(qkvB, ctxB);

    // 3: proj = ctx @ Wo + bo  (-> bf16)
    mfma_gemm<true, 1><<<dim3(D_ / 128, M / 128), blk, 0, stream>>>(
        ctxB, D_, WoT, D_, bo, projB, D_, D_, 0, 0, 0);

    // 4: x1_b = LN(xB + projB)  (bf16 residual read: -32 MB HBM)
    add_ln_kernel<true, true, true><<<dim3(M), blk, 0, stream>>>(xB, projB, g1, be1, x1B);

    // 5+6: FFN chunked over M (2 x 8192 rows); W2 uses KU=2 (BK=64):
    // its 512-block grid caps occupancy at 2 blocks/CU anyway, so the
    // 64 KiB LDS costs nothing and halves the K-loop barrier count.
    for (int mc = 0; mc < 2; ++mc) {
        const size_t m0 = (size_t)mc * 8192;
        mfma_gemm<true, 1><<<dim3(F_ / 128, 8192 / 128), blk, 0, stream>>>(
            x1B + m0 * D_, D_, W1T, D_, b1, hchunk, F_, D_, 1, 0, 0);
        mfma_gemm<true, 2><<<dim3(D_ / 128, 8192 / 128), blk, 0, stream>>>(
            hchunk, F_, W2T, F_, b2, ffnB + m0 * D_, D_, F_, 0, 0, 0);
    }

    // 7: out = LN(x1 + ffn) -> d_out (f32), overwrites scratch
    add_ln_kernel<true, true, false><<<dim3(M), blk, 0, stream>>>(x1B, ffnB, g2, be2, out);
}